// Round 2
// baseline (539.929 us; speedup 1.0000x reference)
//
#include <hip/hip_runtime.h>
#include <math.h>

#define C 64
#define KCOEF 4

__device__ __forceinline__ unsigned enc_f32(float f) {
    unsigned b = __float_as_uint(f);
    return (b & 0x80000000u) ? ~b : (b | 0x80000000u);
}
__device__ __forceinline__ float dec_f32(unsigned k) {
    unsigned b = (k & 0x80000000u) ? (k ^ 0x80000000u) : ~k;
    return __uint_as_float(b);
}

// Kernel A: per node n compute z[n,j,:] = x[n] @ W[j] (j=0..3 -> ws, j=4 -> out + bias),
// and d[n] = x[n] . att_vector
__global__ __launch_bounds__(320) void kA(const float* __restrict__ x,
        const float* __restrict__ W, const float* __restrict__ bias,
        const float* __restrict__ attv,
        float* __restrict__ z, float* __restrict__ dvec,
        float* __restrict__ out_node, int N) {
    __shared__ float xs[C];
    int n = blockIdx.x;
    int tid = threadIdx.x;
    if (tid < C) xs[tid] = x[(size_t)n * C + tid];
    __syncthreads();
    int j = tid >> 6, c = tid & 63;
    const float* Wj = W + (size_t)j * C * C + c;
    float acc = 0.f;
    #pragma unroll
    for (int i = 0; i < C; ++i) acc = fmaf(xs[i], Wj[(size_t)i * C], acc);
    if (j < KCOEF) z[((size_t)n * KCOEF + j) * C + c] = acc;
    else out_node[(size_t)n * C + c] = acc + bias[c];
    if (j == 0) {
        float p = xs[c] * attv[c];
        #pragma unroll
        for (int off = 32; off > 0; off >>= 1) p += __shfl_down(p, off);
        if (c == 0) dvec[n] = p;
    }
}

// Kernel B: per edge raw logit + segment max (order-preserving uint atomicMax)
__global__ __launch_bounds__(256) void kB(const int* __restrict__ src,
        const int* __restrict__ dst,
        const float* __restrict__ ea, const float* __restrict__ dvec,
        float* __restrict__ raw, unsigned* __restrict__ segmax, int E) {
    int e = blockIdx.x * blockDim.x + threadIdx.x;
    if (e >= E) return;
    float4 a = ((const float4*)ea)[e];
    float mean = (a.x + a.y + a.z + a.w) * 0.25f;
    float r = mean * dvec[src[e]];
    raw[e] = r;
    atomicMax(&segmax[dst[e]], enc_f32(r));
}

// Kernel C: exp(raw - max) + segment sum of denominators
__global__ __launch_bounds__(256) void kC(const int* __restrict__ dst,
        const float* __restrict__ raw, const unsigned* __restrict__ segmax,
        float* __restrict__ ex, float* __restrict__ den, int E) {
    int e = blockIdx.x * blockDim.x + threadIdx.x;
    if (e >= E) return;
    int d = dst[e];
    float mx = dec_f32(segmax[d]);
    float v = expf(raw[e] - mx);
    ex[e] = v;
    atomicAdd(&den[d], v);
}

// Kernel D: att score + rank-1 scatter of sum_k (1+att)*ea[e,k]*z[src,k,:]
// One edge per 64-lane wave; lane = channel.
__global__ __launch_bounds__(256) void kD(const int* __restrict__ src,
        const int* __restrict__ dst,
        const float* __restrict__ ea, const float* __restrict__ ex,
        const float* __restrict__ den, const float* __restrict__ z,
        float* __restrict__ out_node, float* __restrict__ out_att, int E) {
    int lane = threadIdx.x & 63;
    int e = blockIdx.x * (blockDim.x >> 6) + (threadIdx.x >> 6);
    if (e >= E) return;
    int s = src[e], d = dst[e];
    float att = ex[e] / (den[d] + 1e-16f);
    if (lane == 0) out_att[e] = att;
    float sc = 1.f + att;
    float4 a = ((const float4*)ea)[e];
    const float* zp = z + (size_t)s * (KCOEF * C) + lane;
    float v = sc * (a.x * zp[0] + a.y * zp[64] + a.z * zp[128] + a.w * zp[192]);
    atomicAdd(&out_node[(size_t)d * C + lane], v);
}

extern "C" void kernel_launch(void* const* d_in, const int* in_sizes, int n_in,
                              void* d_out, int out_size, void* d_ws, size_t ws_size,
                              hipStream_t stream) {
    const float* x    = (const float*)d_in[0];
    const float* ea   = (const float*)d_in[1];
    const float* W    = (const float*)d_in[2];
    const float* bias = (const float*)d_in[3];
    const float* attv = (const float*)d_in[4];
    const int*   ei   = (const int*)d_in[5];

    int N = in_sizes[0] / C;
    int E = in_sizes[5] / 2;
    const int* src = ei;
    const int* dst = ei + E;

    float* out_node = (float*)d_out;
    float* out_att  = (float*)d_out + (size_t)N * C;

    char* ws = (char*)d_ws;
    float* z        = (float*)ws; ws += (size_t)N * KCOEF * C * sizeof(float);
    float* dvec     = (float*)ws; ws += (size_t)N * sizeof(float);
    float* raw      = (float*)ws; ws += (size_t)E * sizeof(float);
    float* exbuf    = (float*)ws; ws += (size_t)E * sizeof(float);
    unsigned* segmax= (unsigned*)ws; ws += (size_t)N * sizeof(unsigned);
    float* den      = (float*)ws; ws += (size_t)N * sizeof(float);

    hipMemsetAsync(segmax, 0, (size_t)N * sizeof(unsigned), stream);
    hipMemsetAsync(den, 0, (size_t)N * sizeof(float), stream);

    kA<<<N, 320, 0, stream>>>(x, W, bias, attv, z, dvec, out_node, N);
    kB<<<(E + 255) / 256, 256, 0, stream>>>(src, dst, ea, dvec, raw, segmax, E);
    kC<<<(E + 255) / 256, 256, 0, stream>>>(dst, raw, segmax, exbuf, den, E);
    kD<<<(E + 3) / 4, 256, 0, stream>>>(src, dst, ea, exbuf, den, z, out_node, out_att, E);
}

// Round 3
// 451.883 us; speedup vs baseline: 1.1948x; 1.1948x over previous
//
#include <hip/hip_runtime.h>
#include <math.h>

#define C 64
#define KCOEF 4

// ---------------- kA: out_node = x @ W[4] + bias ; dvec = x . att_vector ----
// one wave per node, lane = output channel
__global__ __launch_bounds__(256) void kA(const float* __restrict__ x,
        const float* __restrict__ W, const float* __restrict__ bias,
        const float* __restrict__ attv,
        float* __restrict__ dvec, float* __restrict__ out_node, int N) {
    int wv = threadIdx.x >> 6, lane = threadIdx.x & 63;
    int n = blockIdx.x * 4 + wv;
    if (n >= N) return;
    float xr = x[(size_t)n * C + lane];
    const float* W4 = W + (size_t)KCOEF * C * C;
    float acc = 0.f;
    #pragma unroll
    for (int i = 0; i < C; ++i) {
        float xi = __shfl(xr, i);
        acc = fmaf(xi, W4[(size_t)i * C + lane], acc);
    }
    out_node[(size_t)n * C + lane] = acc + bias[lane];
    float p = xr * attv[lane];
    #pragma unroll
    for (int o = 32; o > 0; o >>= 1) p += __shfl_xor(p, o);
    if (lane == 0) dvec[n] = p;
}

// ---------------- kH: degree histogram over dst --------------------------
__global__ __launch_bounds__(256) void kH(const int* __restrict__ dst,
        int* __restrict__ deg, int E) {
    int e = blockIdx.x * 256 + threadIdx.x;
    if (e >= E) return;
    atomicAdd(&deg[dst[e]], 1);
}

// ---------------- scan: off = exclusive_scan(deg) ------------------------
__global__ __launch_bounds__(256) void kS1(const int* __restrict__ deg,
        int* __restrict__ off, int* __restrict__ bsum, int N) {
    int g = blockIdx.x * 256 + threadIdx.x;
    int lane = threadIdx.x & 63, w = threadIdx.x >> 6;
    int v = (g < N) ? deg[g] : 0;
    int incl = v;
    #pragma unroll
    for (int s = 1; s < 64; s <<= 1) {
        int t = __shfl_up(incl, s);
        if (lane >= s) incl += t;
    }
    __shared__ int wtot[4];
    if (lane == 63) wtot[w] = incl;
    __syncthreads();
    int add = 0;
    for (int ww = 0; ww < w; ++ww) add += wtot[ww];
    int excl = incl - v + add;
    if (g < N) off[g] = excl;
    if (threadIdx.x == 255) bsum[blockIdx.x] = excl + v;
}

__global__ __launch_bounds__(256) void kS2(int* __restrict__ bsum, int NB) {
    int t = threadIdx.x;
    int lane = t & 63, w = t >> 6;
    int v = (t < NB) ? bsum[t] : 0;
    int incl = v;
    #pragma unroll
    for (int s = 1; s < 64; s <<= 1) {
        int tt = __shfl_up(incl, s);
        if (lane >= s) incl += tt;
    }
    __shared__ int wtot[4];
    if (lane == 63) wtot[w] = incl;
    __syncthreads();
    int add = 0;
    for (int ww = 0; ww < w; ++ww) add += wtot[ww];
    if (t < NB) bsum[t] = incl - v + add;
}

__global__ __launch_bounds__(256) void kS3(int* __restrict__ off,
        const int* __restrict__ bsum, int* __restrict__ cur, int N) {
    int g = blockIdx.x * 256 + threadIdx.x;
    if (g >= N) return;
    int o = off[g] + bsum[blockIdx.x];
    off[g] = o;
    cur[g] = o;
}

// ---------------- kP: scatter edges into CSR order -----------------------
__global__ __launch_bounds__(256) void kP(const int* __restrict__ src,
        const int* __restrict__ dst, const float* __restrict__ ea,
        const float* __restrict__ dvec, int* __restrict__ cur,
        float* __restrict__ rawS, int* __restrict__ eidS, int E) {
    int e = blockIdx.x * 256 + threadIdx.x;
    if (e >= E) return;
    float4 a = ((const float4*)ea)[e];
    float mean = (a.x + a.y + a.z + a.w) * 0.25f;
    float r = mean * dvec[src[e]];
    int p = atomicAdd(&cur[dst[e]], 1);
    rawS[p] = r;
    eidS[p] = e;
}

// ---------------- kE: per-node softmax + x-space aggregate ---------------
// one wave per dst node; lane = input channel for aggregation
__global__ __launch_bounds__(256) void kE(const float* __restrict__ x,
        const float* __restrict__ ea, const int* __restrict__ src,
        const int* __restrict__ off, const int* __restrict__ deg,
        const float* __restrict__ rawS, const int* __restrict__ eidS,
        float* __restrict__ agg, float* __restrict__ out_att, int N) {
    int wv = __builtin_amdgcn_readfirstlane(threadIdx.x >> 6);
    int lane = threadIdx.x & 63;
    int n = blockIdx.x * 4 + wv;
    if (n >= N) return;
    size_t ab = (size_t)n * (KCOEF * C) + lane;
    int s0 = off[n];
    int dg = deg[n];
    if (dg == 0) {
        agg[ab] = 0.f; agg[ab + 64] = 0.f; agg[ab + 128] = 0.f; agg[ab + 192] = 0.f;
        return;
    }
    // softmax stats over this node's incoming edges (coalesced rawS)
    float m = -INFINITY;
    for (int i = lane; i < dg; i += 64) m = fmaxf(m, rawS[s0 + i]);
    #pragma unroll
    for (int o = 32; o > 0; o >>= 1) m = fmaxf(m, __shfl_xor(m, o));
    float ssum = 0.f;
    for (int i = lane; i < dg; i += 64) ssum += expf(rawS[s0 + i] - m);
    #pragma unroll
    for (int o = 32; o > 0; o >>= 1) ssum += __shfl_xor(ssum, o);
    float inv = 1.f / (ssum + 1e-16f);
    // aggregate: agg[k][c] = sum_e (1+att)*ea[e,k]*x[src_e,c]
    float a0 = 0.f, a1 = 0.f, a2 = 0.f, a3 = 0.f;
    for (int i = 0; i < dg; ++i) {
        int idx = s0 + i;
        float r = rawS[idx];
        int e0 = eidS[idx];
        float att = expf(r - m) * inv;
        int sN = src[e0];
        float4 cf = *(const float4*)(ea + (size_t)e0 * 4);
        float xr = x[(size_t)sN * C + lane];
        float xw = (1.f + att) * xr;
        a0 = fmaf(cf.x, xw, a0);
        a1 = fmaf(cf.y, xw, a1);
        a2 = fmaf(cf.z, xw, a2);
        a3 = fmaf(cf.w, xw, a3);
        if (lane == 0) out_att[e0] = att;
    }
    agg[ab] = a0; agg[ab + 64] = a1; agg[ab + 128] = a2; agg[ab + 192] = a3;
}

// ---------------- kF: out_node += agg[N,256] @ Wflat[256,64] -------------
// block: 64 nodes x 64 channels; each thread: 16 nodes, 1 channel
__global__ __launch_bounds__(256) void kF(const float* __restrict__ agg,
        const float* __restrict__ W, float* __restrict__ out_node, int N) {
    int wv = __builtin_amdgcn_readfirstlane(threadIdx.x >> 6);
    int c  = threadIdx.x & 63;
    int nbase = blockIdx.x * 64 + wv * 16;
    float acc[16];
    int ncl[16];
    #pragma unroll
    for (int j = 0; j < 16; ++j) {
        acc[j] = 0.f;
        int n = nbase + j;
        ncl[j] = (n < N) ? n : (N - 1);
    }
    for (int k = 0; k < KCOEF; ++k) {
        const float* Wk = W + (size_t)k * C * C + c;
        for (int i = 0; i < C; i += 4) {
            float w0 = Wk[(size_t)(i + 0) * C];
            float w1 = Wk[(size_t)(i + 1) * C];
            float w2 = Wk[(size_t)(i + 2) * C];
            float w3 = Wk[(size_t)(i + 3) * C];
            #pragma unroll
            for (int j = 0; j < 16; ++j) {
                const float4 a = *(const float4*)(agg + (size_t)ncl[j] * (KCOEF * C) + k * C + i);
                acc[j] = fmaf(a.x, w0, fmaf(a.y, w1, fmaf(a.z, w2, fmaf(a.w, w3, acc[j]))));
            }
        }
    }
    #pragma unroll
    for (int j = 0; j < 16; ++j) {
        int n = nbase + j;
        if (n < N) out_node[(size_t)n * C + c] += acc[j];
    }
}

extern "C" void kernel_launch(void* const* d_in, const int* in_sizes, int n_in,
                              void* d_out, int out_size, void* d_ws, size_t ws_size,
                              hipStream_t stream) {
    const float* x    = (const float*)d_in[0];
    const float* ea   = (const float*)d_in[1];
    const float* W    = (const float*)d_in[2];
    const float* bias = (const float*)d_in[3];
    const float* attv = (const float*)d_in[4];
    const int*   ei   = (const int*)d_in[5];

    int N = in_sizes[0] / C;
    int E = in_sizes[5] / 2;
    const int* src = ei;
    const int* dst = ei + E;

    float* out_node = (float*)d_out;
    float* out_att  = (float*)d_out + (size_t)N * C;

    char* ws = (char*)d_ws;
    float* agg  = (float*)ws; ws += (size_t)N * KCOEF * C * sizeof(float);
    float* rawS = (float*)ws; ws += (size_t)E * sizeof(float);
    int*   eidS = (int*)ws;   ws += (size_t)E * sizeof(int);
    float* dvec = (float*)ws; ws += (size_t)N * sizeof(float);
    int*   deg  = (int*)ws;   ws += (size_t)N * sizeof(int);
    int*   off  = (int*)ws;   ws += (size_t)N * sizeof(int);
    int*   cur  = (int*)ws;   ws += (size_t)N * sizeof(int);
    int*   bsum = (int*)ws;   ws += 1024;

    int NB = (N + 255) / 256;   // 196 (<256 required for kS2)

    hipMemsetAsync(deg, 0, (size_t)N * sizeof(int), stream);
    kA  <<<(N + 3) / 4, 256, 0, stream>>>(x, W, bias, attv, dvec, out_node, N);
    kH  <<<(E + 255) / 256, 256, 0, stream>>>(dst, deg, E);
    kS1 <<<NB, 256, 0, stream>>>(deg, off, bsum, N);
    kS2 <<<1, 256, 0, stream>>>(bsum, NB);
    kS3 <<<NB, 256, 0, stream>>>(off, bsum, cur, N);
    kP  <<<(E + 255) / 256, 256, 0, stream>>>(src, dst, ea, dvec, cur, rawS, eidS, E);
    kE  <<<(N + 3) / 4, 256, 0, stream>>>(x, ea, src, off, deg, rawS, eidS, agg, out_att, N);
    kF  <<<(N + 63) / 64, 256, 0, stream>>>(agg, W, out_node, N);
}

// Round 5
// 377.585 us; speedup vs baseline: 1.4300x; 1.1968x over previous
//
#include <hip/hip_runtime.h>
#include <math.h>

#define C 64
#define KCOEF 4

// ============ kAH: fused [kA: out=x@W4+bias, dvec=x.attv] + [kH: dst histogram]
__global__ __launch_bounds__(256) void kAH(const float* __restrict__ x,
        const float* __restrict__ W, const float* __restrict__ bias,
        const float* __restrict__ attv, const int* __restrict__ dst,
        float* __restrict__ dvec, float* __restrict__ out_node,
        int* __restrict__ deg, int N, int E, int NBA) {
    if ((int)blockIdx.x < NBA) {
        int wv = threadIdx.x >> 6, lane = threadIdx.x & 63;
        int n = blockIdx.x * 4 + wv;
        if (n >= N) return;
        float xr = x[(size_t)n * C + lane];
        const float* W4 = W + (size_t)KCOEF * C * C;
        float acc = 0.f;
        #pragma unroll
        for (int i = 0; i < C; ++i) {
            float xi = __shfl(xr, i);
            acc = fmaf(xi, W4[(size_t)i * C + lane], acc);
        }
        out_node[(size_t)n * C + lane] = acc + bias[lane];
        float p = xr * attv[lane];
        #pragma unroll
        for (int o = 32; o > 0; o >>= 1) p += __shfl_xor(p, o);
        if (lane == 0) dvec[n] = p;
    } else {
        int e = ((int)blockIdx.x - NBA) * 256 + (int)threadIdx.x;
        if (e >= E) return;
        atomicAdd(&deg[dst[e]], 1);
    }
}

// ============ scan over deg -> off ============
__global__ __launch_bounds__(256) void kS1(const int* __restrict__ deg,
        int* __restrict__ off, int* __restrict__ bsum, int N) {
    int g = blockIdx.x * 256 + threadIdx.x;
    int lane = threadIdx.x & 63, w = threadIdx.x >> 6;
    int v = (g < N) ? deg[g] : 0;
    int incl = v;
    #pragma unroll
    for (int s = 1; s < 64; s <<= 1) {
        int t = __shfl_up(incl, s);
        if (lane >= s) incl += t;
    }
    __shared__ int wtot[4];
    if (lane == 63) wtot[w] = incl;
    __syncthreads();
    int add = 0;
    for (int ww = 0; ww < w; ++ww) add += wtot[ww];
    int excl = incl - v + add;
    if (g < N) off[g] = excl;
    if (threadIdx.x == 255) bsum[blockIdx.x] = excl + v;
}

__global__ __launch_bounds__(256) void kS2(int* __restrict__ bsum, int NB) {
    int t = threadIdx.x;
    int lane = t & 63, w = t >> 6;
    int v = (t < NB) ? bsum[t] : 0;
    int incl = v;
    #pragma unroll
    for (int s = 1; s < 64; s <<= 1) {
        int tt = __shfl_up(incl, s);
        if (lane >= s) incl += tt;
    }
    __shared__ int wtot[4];
    if (lane == 63) wtot[w] = incl;
    __syncthreads();
    int add = 0;
    for (int ww = 0; ww < w; ++ww) add += wtot[ww];
    if (t < NB) bsum[t] = incl - v + add;
}

__global__ __launch_bounds__(256) void kS3(int* __restrict__ off,
        const int* __restrict__ bsum, int* __restrict__ cur, int N) {
    int g = blockIdx.x * 256 + threadIdx.x;
    if (g >= N) return;
    int o = off[g] + bsum[blockIdx.x];
    off[g] = o;
    cur[g] = o;
}

// ============ kP: CSR scatter of raw logits + edge ids ============
__global__ __launch_bounds__(256) void kP(const int* __restrict__ src,
        const int* __restrict__ dst, const float* __restrict__ ea,
        const float* __restrict__ dvec, int* __restrict__ cur,
        float* __restrict__ rawS, int* __restrict__ eidS, int E) {
    int e = blockIdx.x * 256 + threadIdx.x;
    if (e >= E) return;
    float4 a = ((const float4*)ea)[e];
    float mean = (a.x + a.y + a.z + a.w) * 0.25f;
    float r = mean * dvec[src[e]];
    int p = atomicAdd(&cur[dst[e]], 1);
    rawS[p] = r;
    eidS[p] = e;
}

// ============ kE2: per-node softmax stats + batched x-space aggregation ====
// one wave per dst node. Batch of <=64 edges staged in wave-private LDS.
__global__ __launch_bounds__(256) void kE2(const float* __restrict__ x,
        const float* __restrict__ ea, const int* __restrict__ src,
        const int* __restrict__ off,
        const int* degp, float* invOut,          // aliased (deg buffer)
        const float* __restrict__ rawS, const int* __restrict__ eidS,
        float* mOut,                              // aliased (cur buffer)
        float* __restrict__ agg, int N) {
    __shared__ float sb[4][64][8];   // [wave][edge][ea4*w, byteoff, pad...]
    int wv = __builtin_amdgcn_readfirstlane(threadIdx.x >> 6);
    int lane = threadIdx.x & 63;
    int n = blockIdx.x * 4 + wv;
    if (n >= N) return;
    int s0 = off[n];
    int dg = degp[n];
    size_t ab = (size_t)n * (KCOEF * C) + lane;
    if (dg == 0) {
        agg[ab] = 0.f; agg[ab + 64] = 0.f; agg[ab + 128] = 0.f; agg[ab + 192] = 0.f;
        if (lane == 0) { mOut[n] = 0.f; invOut[n] = 1.f; }
        return;
    }
    // pass 1: segment max (coalesced rawS)
    float m = -INFINITY;
    for (int b = 0; b < dg; b += 64) {
        int i = b + lane;
        if (i < dg) m = fmaxf(m, rawS[s0 + i]);
    }
    #pragma unroll
    for (int o = 32; o > 0; o >>= 1) m = fmaxf(m, __shfl_xor(m, o));
    // pass 2: denom
    float ss = 0.f;
    for (int b = 0; b < dg; b += 64) {
        int i = b + lane;
        if (i < dg) ss += expf(rawS[s0 + i] - m);
    }
    #pragma unroll
    for (int o = 32; o > 0; o >>= 1) ss += __shfl_xor(ss, o);
    float inv = 1.f / (ss + 1e-16f);
    if (lane == 0) { mOut[n] = m; invOut[n] = inv; }
    // pass 3: aggregate
    float a0 = 0.f, a1 = 0.f, a2 = 0.f, a3 = 0.f;
    const char* xl = (const char*)x + (size_t)lane * 4;
    for (int b = 0; b < dg; b += 64) {
        int i = b + lane;
        int blen = min(64, dg - b);
        if (i < dg) {
            int e0 = eidS[s0 + i];
            int sN = src[e0];
            float4 c4 = *(const float4*)(ea + (size_t)e0 * 4);
            float w = 1.f + expf(rawS[s0 + i] - m) * inv;
            sb[wv][lane][0] = c4.x * w;
            sb[wv][lane][1] = c4.y * w;
            sb[wv][lane][2] = c4.z * w;
            sb[wv][lane][3] = c4.w * w;
            ((int*)&sb[wv][lane][0])[4] = sN * (C * 4);  // byte offset of x row
        }
        // wave-synchronous: same-wave ds_write -> ds_read, compiler inserts waits
        #pragma unroll 4
        for (int j = 0; j < blen; ++j) {
            float4 e4 = *(const float4*)&sb[wv][j][0];
            int ob = ((const int*)&sb[wv][j][0])[4];
            float xr = *(const float*)(xl + ob);
            a0 = fmaf(e4.x, xr, a0);
            a1 = fmaf(e4.y, xr, a1);
            a2 = fmaf(e4.z, xr, a2);
            a3 = fmaf(e4.w, xr, a3);
        }
    }
    agg[ab] = a0; agg[ab + 64] = a1; agg[ab + 128] = a2; agg[ab + 192] = a3;
}

// ============ kFT: fused [kF: out += agg @ W[:4]] + [kT: coalesced out_att] ==
__global__ __launch_bounds__(256) void kFT(const float* __restrict__ agg,
        const float* __restrict__ W, float* __restrict__ out_node,
        const int* __restrict__ src, const int* __restrict__ dst,
        const float* __restrict__ ea, const float* __restrict__ dvec,
        const float* __restrict__ mA, const float* __restrict__ invA,
        float* __restrict__ out_att, int N, int E, int NBF) {
    if ((int)blockIdx.x < NBF) {
        int wv = __builtin_amdgcn_readfirstlane(threadIdx.x >> 6);
        int c  = threadIdx.x & 63;
        int nbase = blockIdx.x * 64 + wv * 16;
        float acc[16];
        int ncl[16];
        #pragma unroll
        for (int j = 0; j < 16; ++j) {
            acc[j] = 0.f;
            int n = nbase + j;
            ncl[j] = (n < N) ? n : (N - 1);
        }
        for (int k = 0; k < KCOEF; ++k) {
            const float* Wk = W + (size_t)k * C * C + c;
            for (int i = 0; i < C; i += 4) {
                float w0 = Wk[(size_t)(i + 0) * C];
                float w1 = Wk[(size_t)(i + 1) * C];
                float w2 = Wk[(size_t)(i + 2) * C];
                float w3 = Wk[(size_t)(i + 3) * C];
                #pragma unroll
                for (int j = 0; j < 16; ++j) {
                    const float4 a = *(const float4*)(agg + (size_t)ncl[j] * (KCOEF * C) + k * C + i);
                    acc[j] = fmaf(a.x, w0, fmaf(a.y, w1, fmaf(a.z, w2, fmaf(a.w, w3, acc[j]))));
                }
            }
        }
        #pragma unroll
        for (int j = 0; j < 16; ++j) {
            int n = nbase + j;
            if (n < N) out_node[(size_t)n * C + c] += acc[j];
        }
    } else {
        int e = ((int)blockIdx.x - NBF) * 256 + (int)threadIdx.x;
        if (e >= E) return;
        float4 a = ((const float4*)ea)[e];
        float mean = (a.x + a.y + a.z + a.w) * 0.25f;
        float r = mean * dvec[src[e]];          // bitwise-identical to kP's logit
        int d = dst[e];
        out_att[e] = expf(r - mA[d]) * invA[d];
    }
}

extern "C" void kernel_launch(void* const* d_in, const int* in_sizes, int n_in,
                              void* d_out, int out_size, void* d_ws, size_t ws_size,
                              hipStream_t stream) {
    const float* x    = (const float*)d_in[0];
    const float* ea   = (const float*)d_in[1];
    const float* W    = (const float*)d_in[2];
    const float* bias = (const float*)d_in[3];
    const float* attv = (const float*)d_in[4];
    const int*   ei   = (const int*)d_in[5];

    int N = in_sizes[0] / C;
    int E = in_sizes[5] / 2;
    const int* src = ei;
    const int* dst = ei + E;

    float* out_node = (float*)d_out;
    float* out_att  = (float*)d_out + (size_t)N * C;

    char* ws = (char*)d_ws;
    float* agg  = (float*)ws; ws += (size_t)N * KCOEF * C * sizeof(float);
    float* rawS = (float*)ws; ws += (size_t)E * sizeof(float);
    int*   eidS = (int*)ws;   ws += (size_t)E * sizeof(int);
    float* dvec = (float*)ws; ws += (size_t)N * sizeof(float);
    int*   deg  = (int*)ws;   ws += (size_t)N * sizeof(int);
    int*   off  = (int*)ws;   ws += (size_t)N * sizeof(int);
    int*   cur  = (int*)ws;   ws += (size_t)N * sizeof(int);
    int*   bsum = (int*)ws;   ws += 1024;

    // overlays (dead-after-use buffers reused for softmax stats)
    float* mA   = (float*)cur;   // cur dead after kP
    float* invA = (float*)deg;   // deg dead after kE2 reads it (same kernel writes inv)

    int NB  = (N + 255) / 256;       // scan blocks (196 <= 256)
    int NBA = (N + 3) / 4;           // kA waves-blocks
    int NBH = (E + 255) / 256;       // histogram blocks
    int NBF = (N + 63) / 64;         // kF blocks
    int NBT = (E + 255) / 256;       // kT blocks

    hipMemsetAsync(deg, 0, (size_t)N * sizeof(int), stream);
    kAH <<<NBA + NBH, 256, 0, stream>>>(x, W, bias, attv, dst, dvec, out_node, deg, N, E, NBA);
    kS1 <<<NB, 256, 0, stream>>>(deg, off, bsum, N);
    kS2 <<<1, 256, 0, stream>>>(bsum, NB);
    kS3 <<<NB, 256, 0, stream>>>(off, bsum, cur, N);
    kP  <<<(E + 255) / 256, 256, 0, stream>>>(src, dst, ea, dvec, cur, rawS, eidS, E);
    kE2 <<<(N + 3) / 4, 256, 0, stream>>>(x, ea, src, off, deg, invA, rawS, eidS, mA, agg, N);
    kFT <<<NBF + NBT, 256, 0, stream>>>(agg, W, out_node, src, dst, ea, dvec, mA, invA, out_att, N, E, NBF);
}